// Round 9
// baseline (84.351 us; speedup 1.0000x reference)
//
#include <hip/hip_runtime.h>
#include <cstdint>

namespace {

constexpr int BB = 64;
constexpr int DDIM = 196608;          // 3*256*256
constexpr float T_SCALE = 0.99f;      // 1 - 1/MAX_TIMESTEPS

// ws layout (floats). Per-block partials in bigp mirror ws offsets for idx<NRED.
constexpr int WS_ZD   = 0;            // 64*64  ZD[i][j] = z_i . d_j
constexpr int WS_DD   = 4096;         // 64*64  DD[i][j] = d_i . d_j
constexpr int WS_Z2   = 8192;         // 64     |z_i|^2
constexpr int WS_ELEM = 8256;         // 1      elementwise loss total
constexpr int NRED    = 8257;
constexpr int WS_BIGP = 8384;
constexpr int PSTRIDE = 8272;         // per-block stride (16B aligned)

using f32x4  = __attribute__((ext_vector_type(4))) float;
using bf16x8 = __attribute__((ext_vector_type(8))) __bf16;

__device__ inline f32x4 MFMA(bf16x8 a, bf16x8 b, f32x4 c) {
  return __builtin_amdgcn_mfma_f32_16x16x32_bf16(a, b, c, 0, 0, 0);
}

__global__ void k_init(float* __restrict__ ws) {
  int idx = blockIdx.x * 256 + threadIdx.x;
  if (idx < NRED) ws[idx] = 0.0f;
}

// ---------------------------------------------------------------------------
// k_main: dual Grams (bf16 3-split) + z2 + elem loss. 512 thr / 8 waves.
//   ZD = zh(dh+dm+dl)+zm(dh+dm)+zl*dh ; DD same with d on both sides.
// Subtile = 32 k. DOUBLE-BUFFERED LDS -> ONE barrier per subtile (R7 had 2;
//   each barrier's implicit vmcnt(0) drain is the structural stall).
// LDS: per buf, 3 spaces of [64 rows][128 B], each holding 2 tiles of 4
//   16B-chunks: (zh|zm), (zl|dh), (dm|dl). Global chunk c in 0..7, XOR
//   swizzle c^(r&7) -- exactly R7's measured-0-conflict pattern.
// Waves: g=wv>>2 (0 ZD, 1 DD), row-band m0=(wv&3)*16, full K -> no k-split,
//   24 MFMA + 15 ds_read_b128 per wave per subtile.
// Register budget (the R3-R7 lesson): K=32 staging = 1 float4/stream;
//   splits written to LDS immediately (no reg buffering); pm/plv transient.
//   Demand ~56 arch VGPR + 16 acc -> fits even the allocator's 64 choice.
// ---------------------------------------------------------------------------
template <int SUBT, bool ATOMIC>
__global__ __launch_bounds__(512) void k_main(
    const float* __restrict__ data, const float* __restrict__ noise,
    const float* __restrict__ pmean, const float* __restrict__ plogv,
    float* __restrict__ ws, float* __restrict__ bigp) {
  __shared__ __align__(16) char lds[49152];   // 2 bufs x 3 spaces x 8 KB
  __shared__ float esm[8];

  const int t  = threadIdx.x;
  const int wv = t >> 6;
  const int l  = t & 63;
  const int g  = wv >> 2;              // 0: ZD, 1: DD
  const int m0 = (wv & 3) << 4;        // output row-band
  const int r  = t >> 3;               // staging row 0..63
  const int c4 = t & 7;                // staging 4-float chunk
  const int chunk0 = blockIdx.x * (SUBT * 32);
  float* dst = ATOMIC ? ws : (bigp + (size_t)blockIdx.x * PSTRIDE);

  f32x4 acc[4];
#pragma unroll
  for (int b = 0; b < 4; ++b) acc[b] = 0.0f;
  float z2acc = 0.0f, eacc = 0.0f;
  float4 dv, zv;                       // current staging regs (1 float4 each)

  auto LOADDZ = [&](int s) {
    const size_t off = (size_t)r * DDIM + chunk0 + (s << 5) + (c4 << 2);
    dv = *(const float4*)(data  + off);
    zv = *(const float4*)(noise + off);
  };

  // split 4 floats of v into tiles tbase..tbase+2 of buffer `buf`, write now
  auto SPLITW = [&](int buf, const float4& v, int tbase) {
    const float* f = (const float*)&v;
    uint32_t h[2], m[2], lo[2];
#pragma unroll
    for (int p = 0; p < 2; ++p) {
      const float a = f[2 * p], b = f[2 * p + 1];
      const uint32_t ha = __float_as_uint(a) & 0xFFFF0000u;
      const uint32_t hb = __float_as_uint(b) & 0xFFFF0000u;
      h[p] = (ha >> 16) | hb;
      const float ra = a - __uint_as_float(ha);
      const float rb = b - __uint_as_float(hb);
      const uint32_t ma = __float_as_uint(ra) & 0xFFFF0000u;
      const uint32_t mb = __float_as_uint(rb) & 0xFFFF0000u;
      m[p] = (ma >> 16) | mb;
      const float sa = ra - __uint_as_float(ma);
      const float sb = rb - __uint_as_float(mb);
      lo[p] = (__float_as_uint(sa) >> 16) | (__float_as_uint(sb) & 0xFFFF0000u);
    }
#pragma unroll
    for (int sp = 0; sp < 3; ++sp) {
      const int tile = tbase + sp;
      const int byte = buf + ((tile >> 1) << 13) + (r << 7) +
                       (((((tile & 1) << 2) + (c4 >> 1)) ^ (r & 7)) << 4) +
                       ((c4 & 1) << 3);
      const uint32_t* pk = (sp == 0) ? h : (sp == 1) ? m : lo;
      *(uint2*)(lds + byte) = uint2{pk[0], pk[1]};
    }
  };

  auto STAGE = [&](int s) {            // split-write + elem + z2 for tile s
    const int buf = (s & 1) * 24576;
    const size_t off = (size_t)r * DDIM + chunk0 + (s << 5) + (c4 << 2);
    const float4 pm4 = *(const float4*)(pmean + off);
    const float4 pl4 = *(const float4*)(plogv + off);
    SPLITW(buf, zv, 0);
    SPLITW(buf, dv, 3);
    const float* df = (const float*)&dv;
    const float* zf = (const float*)&zv;
    const float* pf = (const float*)&pm4;
    const float* gf = (const float*)&pl4;
#pragma unroll
    for (int p = 0; p < 4; ++p) {
      const float d = df[p], z = zf[p], pm = pf[p], pl = gf[p];
      eacc += 0.5f * (pm * pm + __expf(pl) * pl) - pm * (d - z);
      z2acc += z * z;
    }
  };

  auto FRAG = [&](int buf, int tile, int row) -> bf16x8 {
    const int byte = buf + ((tile >> 1) << 13) + (row << 7) +
                     (((((tile & 1) << 2) + (l >> 4)) ^ (row & 7)) << 4);
    return *(const bf16x8*)(lds + byte);
  };

  auto MMA = [&](int s) {
    const int buf = (s & 1) * 24576;
    const int ar  = m0 + (l & 15);
    bf16x8 af[3];
#pragma unroll
    for (int sp = 0; sp < 3; ++sp) af[sp] = FRAG(buf, g * 3 + sp, ar);
#pragma unroll
    for (int b = 0; b < 4; ++b) {
      const int br = (b << 4) + (l & 15);
      bf16x8 bd[3];
#pragma unroll
      for (int sp = 0; sp < 3; ++sp) bd[sp] = FRAG(buf, 3 + sp, br);
      acc[b] = MFMA(af[0], bd[0], acc[b]);
      acc[b] = MFMA(af[0], bd[1], acc[b]);
      acc[b] = MFMA(af[1], bd[0], acc[b]);
      acc[b] = MFMA(af[1], bd[1], acc[b]);
      acc[b] = MFMA(af[0], bd[2], acc[b]);
      acc[b] = MFMA(af[2], bd[0], acc[b]);
    }
  };

  // prologue: stage tile 0 into buf0, start loads for tile 1
  LOADDZ(0);
  STAGE(0);
  LOADDZ(1);
  __syncthreads();                     // buf0 ready; dz(1) complete (drain)

  for (int s = 0; s < SUBT; ++s) {
    if (s + 1 < SUBT) {
      STAGE(s + 1);                    // writes buf[(s+1)&1], uses dz regs
      if (s + 2 < SUBT) LOADDZ(s + 2); // issue next loads
    }
    MMA(s);                            // reads buf[s&1]
    __syncthreads();                   // single drain point per subtile
  }

  // ---- z2 (8 staging lanes per row) / elem reductions ----
  {
    float v = z2acc;
    v += __shfl_xor(v, 1);
    v += __shfl_xor(v, 2);
    v += __shfl_xor(v, 4);
    if ((l & 7) == 0) {
      if (ATOMIC) atomicAdd(ws + WS_Z2 + r, v);
      else        dst[WS_Z2 + r] = v;
    }
  }
  {
    float ev = eacc;
#pragma unroll
    for (int m = 1; m <= 32; m <<= 1) ev += __shfl_xor(ev, m);
    if (l == 0) esm[wv] = ev;
  }
  __syncthreads();
  if (t == 0) {
    float s0 = 0.f;
#pragma unroll
    for (int e = 0; e < 8; ++e) s0 += esm[e];
    if (ATOMIC) atomicAdd(ws + WS_ELEM, s0);
    else        dst[WS_ELEM] = s0;
  }

  // ---- gram stores: C/D layout col=lane&15, row=4*(lane>>4)+reg ----
  const int grOff = (g == 0) ? WS_ZD : WS_DD;
#pragma unroll
  for (int b = 0; b < 4; ++b)
#pragma unroll
    for (int rg = 0; rg < 4; ++rg) {
      const int row = m0 + ((l >> 4) << 2) + rg;
      const int col = (b << 4) + (l & 15);
      if (ATOMIC) atomicAdd(ws + grOff + row * 64 + col, acc[b][rg]);
      else        dst[grOff + row * 64 + col] = acc[b][rg];
    }
}

// Fold NB per-block partials into ws[0..NRED). 8-way atomic contention only.
__global__ void k_reduce(const float* __restrict__ bigp, float* __restrict__ ws,
                         int nb) {
  const int idx = blockIdx.x * 64 + threadIdx.x;
  if (idx >= NRED) return;
  const int per = nb >> 3;
  const size_t b0 = (size_t)blockIdx.y * per;
  float s = 0.f;
#pragma unroll 4
  for (int b = 0; b < per; ++b)
    s += bigp[(b0 + b) * PSTRIDE + idx];
  atomicAdd(ws + idx, s);
}

// ---------------------------------------------------------------------------
// k_smallfinal (merged k_small + k_final, one block of 1024):
//  wave wv handles rows 4wv..4wv+3; per row i:
//   cross_ij = (1-t) ZD[i][j] + t DD[i][j]; softmax over logits (f64);
//   sum_k u^2 = (w^T DD w - 2 w.cross_i + n2_i)/(1-t+eps)^2,
//   n2_i = (1-t)^2 z2_i + 2t(1-t) ZD[i][i] + t^2 DD[i][i].
//  Then block-reduce: out = (0.5*sum_i u2_i + elem) / (BB*DDIM).
// ---------------------------------------------------------------------------
__global__ __launch_bounds__(1024) void k_smallfinal(
    const float* __restrict__ times, const float* __restrict__ ws,
    float* __restrict__ out) {
  __shared__ double u2s[64];
  const int t = threadIdx.x;
  const int wv = t >> 6;
  const int j = t & 63;

#pragma unroll
  for (int ii = 0; ii < 4; ++ii) {
    const int i = (wv << 2) + ii;
    const double tt = (double)(times[i] * T_SCALE);
    const double omt = 1.0 - tt;
    const double var = omt * omt + 1e-8;
    const double inv2v = 1.0 / (2.0 * var);
    const double zd = (double)ws[WS_ZD + (i << 6) + j];
    const double dd = (double)ws[WS_DD + (i << 6) + j];
    const double cross = omt * zd + tt * dd;
    const double d2j = (double)ws[WS_DD + j * 65];
    const double lg = (2.0 * tt * cross - tt * tt * d2j) * inv2v;
    double m = lg;
#pragma unroll
    for (int msk = 1; msk <= 32; msk <<= 1) m = fmax(m, __shfl_xor(m, msk));
    const double e = exp(lg - m);
    double S = e;
#pragma unroll
    for (int msk = 1; msk <= 32; msk <<= 1) S += __shfl_xor(S, msk);
    const double wgt = e / S;

    // inner_j = sum_j2 wgt_j2 * DD[j][j2] via wave broadcast
    double inner = 0.0;
#pragma unroll 8
    for (int j2 = 0; j2 < 64; ++j2)
      inner += __shfl(wgt, j2) * (double)ws[WS_DD + (j << 6) + j2];
    double s1 = wgt * inner;
    double s2 = wgt * cross;
#pragma unroll
    for (int msk = 1; msk <= 32; msk <<= 1) {
      s1 += __shfl_xor(s1, msk);
      s2 += __shfl_xor(s2, msk);
    }
    if (j == 0) {
      const double zdii = (double)ws[WS_ZD + i * 65];
      const double d2i  = (double)ws[WS_DD + i * 65];
      const double z2i  = (double)ws[WS_Z2 + i];
      const double n2 = omt * omt * z2i + 2.0 * tt * omt * zdii + tt * tt * d2i;
      const double den = omt + 1e-8;
      u2s[i] = (s1 - 2.0 * s2 + n2) / (den * den);
    }
  }
  __syncthreads();
  if (wv == 0) {
    double v = 0.5 * u2s[j];
    if (j == 0) v += (double)ws[WS_ELEM];
#pragma unroll
    for (int m = 1; m <= 32; m <<= 1) v += __shfl_xor(v, m);
    if (j == 0) out[0] = (float)(v / (double)((size_t)BB * DDIM));
  }
}

}  // namespace

extern "C" void kernel_launch(void* const* d_in, const int* in_sizes, int n_in,
                              void* d_out, int out_size, void* d_ws, size_t ws_size,
                              hipStream_t stream) {
  const float* data  = (const float*)d_in[0];
  const float* noise = (const float*)d_in[1];
  const float* times = (const float*)d_in[2];
  const float* pmean = (const float*)d_in[3];
  const float* plogv = (const float*)d_in[4];
  float* out = (float*)d_out;
  float* ws  = (float*)d_ws;
  float* bigp = ws + WS_BIGP;

  const bool fits512 =
      ws_size >= ((size_t)WS_BIGP + (size_t)512 * PSTRIDE) * sizeof(float);

  k_init<<<dim3(33), dim3(256), 0, stream>>>(ws);
  if (fits512) {
    k_main<12, false><<<dim3(512), dim3(512), 0, stream>>>(
        data, noise, pmean, plogv, ws, bigp);
    k_reduce<<<dim3(130, 8), dim3(64), 0, stream>>>(bigp, ws, 512);
  } else {
    k_main<12, true><<<dim3(512), dim3(512), 0, stream>>>(
        data, noise, pmean, plogv, ws, bigp);
  }
  k_smallfinal<<<dim3(1), dim3(1024), 0, stream>>>(times, ws, out);
}